// Round 8
// baseline (518.335 us; speedup 1.0000x reference)
//
#include <hip/hip_runtime.h>

#define NB 8
#define NN 20000
#define FI 128
#define FO 128
#define NE 320000
#define ROWS (NB * NN)        // 160000 flattened (b,n) rows
#define LRALPHA 0.2f
#define ELLW 96               // max degree slot; Poisson(16) tail ~1e-43
#define NBLK 1024             // 4 blocks/CU x 256 CU: guaranteed co-resident
#define NTHR 256
#define LDW 136               // padded LDS stride (2-way bank alias, free)

typedef short bf16x8 __attribute__((ext_vector_type(8)));
typedef float f32x4 __attribute__((ext_vector_type(4)));

static __device__ __forceinline__ float b2f(unsigned short u) {
  return __uint_as_float(((unsigned int)u) << 16);
}
static __device__ __forceinline__ unsigned short f2b(float f) {
  unsigned int u = __float_as_uint(f);
  return (unsigned short)((u + 0x7FFFu + ((u >> 16) & 1u)) >> 16);  // RNE
}

// ---- init: W transpose->bf16, zero ELL cursor, zero grid barrier ----------
__global__ __launch_bounds__(256) void init_kernel(const float* __restrict__ W,
                                                   unsigned short* __restrict__ Wb,
                                                   int* __restrict__ cursor,
                                                   unsigned int* __restrict__ bar) {
  int idx = blockIdx.x * 256 + threadIdx.x;  // 80 blocks -> 20480 threads
  if (idx < FI * FO) {
    int k = idx >> 7, o = idx & 127;
    Wb[o * 128 + k] = f2b(W[idx]);
  }
  if (idx < NN) cursor[idx] = 0;
  if (idx < 8) bar[idx] = 0;
}

// ---- persistent fused kernel: scatter + gemm -> grid barrier -> gather -----
// Co-residency: LDS 34816B -> 4 blocks/CU; launch_bounds(256,4) forces
// VGPR<=128 -> 16 waves/CU. 1024 blocks == exactly the resident capacity.
__global__ __launch_bounds__(NTHR, 4) void mega_kernel(
    const float* __restrict__ x, const unsigned short* __restrict__ Wb,
    const float* __restrict__ a, const int* __restrict__ src,
    const int* __restrict__ dst, unsigned short* __restrict__ hb,
    float* __restrict__ g1, float* __restrict__ g2, int* __restrict__ cursor,
    int* __restrict__ ell, unsigned int* __restrict__ bar,
    float* __restrict__ out) {
  __shared__ __align__(16) unsigned short Ws[128 * LDW];  // 34.8 KB
  const int tid = threadIdx.x;
  const int bid = blockIdx.x;
  const int wv = tid >> 6;
  const int lane = tid & 63;

  // ---- phase A: ELL scatter (independent of gemm; issue its atomics early)
  for (int e = bid * NTHR + tid; e < NE; e += NBLK * NTHR) {
    int s = src[e];
    int d = dst[e];
    int slot = atomicAdd(&cursor[s], 1);
    if (slot < ELLW) ell[s * ELLW + slot] = d;  // overflow impossible; clamped
  }

  // ---- phase B: GEMM, W staged into LDS ONCE per persistent block ----------
  {
    const bf16x8* wsrc = (const bf16x8*)Wb;
#pragma unroll
    for (int it = 0; it < 8; ++it) {
      int c = tid + it * 256;          // 16B chunk id, 0..2047
      int o = c >> 4, seg = c & 15;
      *(bf16x8*)&Ws[o * LDW + seg * 8] = wsrc[c];
    }
    __syncthreads();
    const int m = lane & 15;
    const int quad = lane >> 4;
    float a1v[8], a2v[8];
#pragma unroll
    for (int c = 0; c < 8; ++c) {
      a1v[c] = a[c * 16 + m];
      a2v[c] = a[128 + c * 16 + m];
    }
    for (int t = bid; t < ROWS / 64; t += NBLK) {   // 2500 row-tiles
      const size_t row0 = (size_t)t * 64 + wv * 16;
      const float* xr = x + (row0 + m) * 128;
      bf16x8 afr[4];
#pragma unroll
      for (int k0 = 0; k0 < 4; ++k0) {
        const float4* xp = (const float4*)(xr + k0 * 32 + quad * 8);
        float4 v0 = xp[0], v1 = xp[1];
        union { bf16x8 v; unsigned short u[8]; } af;
        af.u[0] = f2b(v0.x); af.u[1] = f2b(v0.y);
        af.u[2] = f2b(v0.z); af.u[3] = f2b(v0.w);
        af.u[4] = f2b(v1.x); af.u[5] = f2b(v1.y);
        af.u[6] = f2b(v1.z); af.u[7] = f2b(v1.w);
        afr[k0] = af.v;
      }
      f32x4 acc[8] = {};
#pragma unroll
      for (int k0 = 0; k0 < 4; ++k0)
#pragma unroll
        for (int c = 0; c < 8; ++c) {
          bf16x8 bf = *(const bf16x8*)&Ws[(c * 16 + m) * LDW + k0 * 32 + quad * 8];
          acc[c] = __builtin_amdgcn_mfma_f32_16x16x32_bf16(afr[k0], bf, acc[c], 0, 0, 0);
        }
      // C/D layout: col = lane&15 (within c-tile), row = quad*4 + r
      unsigned short* hp = hb + row0 * 128;
#pragma unroll
      for (int c = 0; c < 8; ++c)
#pragma unroll
        for (int r = 0; r < 4; ++r)
          hp[(quad * 4 + r) * 128 + c * 16 + m] = f2b(acc[c][r]);
      float p1[4] = {}, p2[4] = {};
#pragma unroll
      for (int c = 0; c < 8; ++c)
#pragma unroll
        for (int r = 0; r < 4; ++r) {
          p1[r] = fmaf(acc[c][r], a1v[c], p1[r]);
          p2[r] = fmaf(acc[c][r], a2v[c], p2[r]);
        }
#pragma unroll
      for (int off = 1; off < 16; off <<= 1)
#pragma unroll
        for (int r = 0; r < 4; ++r) {
          p1[r] += __shfl_xor(p1[r], off, 64);
          p2[r] += __shfl_xor(p2[r], off, 64);
        }
      if (m == 0) {
        size_t rbase = row0 + quad * 4;
#pragma unroll
        for (int r = 0; r < 4; ++r) {
          g1[rbase + r] = p1[r];
          g2[rbase + r] = p2[r];
        }
      }
    }
  }

  // ---- grid barrier: count-to-NBLK, device-scope fences --------------------
  __syncthreads();
  if (tid == 0) {
    __threadfence();                       // release: drain + wbL2 (cross-XCD)
    atomicAdd(&bar[0], 1u);
    while (atomicAdd(&bar[0], 0u) < NBLK) __builtin_amdgcn_s_sleep(4);
    __threadfence();                       // acquire: invalidate L1/L2
  }
  __syncthreads();

  // ---- phase C: gather; block pinned to XCD bid&7 = its batch --------------
  {
    const int b = bid & 7;
    const float* g1b = g1 + (size_t)b * NN;
    const float* g2b = g2 + (size_t)b * NN;
    const char* hrow = (const char*)(hb + (size_t)b * NN * 128) + lane * 4;
    for (int i = (bid >> 3) * 4 + wv; i < NN; i += (NBLK / 8) * 4) {
      const int deg = min(cursor[i], ELLW);   // >= 1 (src contains arange(N))
      const int base = i * ELLW;
      const float g1i = g1b[i];
      float accLo = 0.f, accHi = 0.f;
      float rs = 0.f;
      for (int c0 = 0; c0 < deg; c0 += 64) {
        const int cnt = min(64, deg - c0);
        const int li = lane < cnt ? lane : cnt - 1;
        const int dvec = ell[base + c0 + li];  // coalesced dst-index chunk
        float w = 0.f;
        if (lane < cnt) {
          float sv = g1i + g2b[dvec];          // L2-resident 4B gather
          float sc = fmaxf(sv, LRALPHA * sv);
          w = __expf(-sc);
        }
        rs += w;
        const int cr = (cnt + 3) & ~3;         // pad: lanes >= cnt carry w=0
        for (int j = 0; j < cr; j += 4) {
#pragma unroll
          for (int jj = 0; jj < 4; ++jj) {
            float wj = __shfl(w, j + jj, 64);
            int dj = __shfl(dvec, j + jj, 64);
            unsigned int u = *(const unsigned int*)(hrow + ((size_t)dj << 8));
            accLo = fmaf(wj, __uint_as_float(u << 16), accLo);
            accHi = fmaf(wj, __uint_as_float(u & 0xFFFF0000u), accHi);
          }
        }
      }
#pragma unroll
      for (int off = 1; off < 64; off <<= 1) rs += __shfl_xor(rs, off, 64);
      const float inv = 1.f / rs;
      float v0 = accLo * inv;
      float v1 = accHi * inv;
      float o0 = v0 > 0.f ? v0 : __expf(v0) - 1.f;   // elu (alpha=1)
      float o1 = v1 > 0.f ? v1 : __expf(v1) - 1.f;
      float2* op = (float2*)(out + ((size_t)b * NN + i) * 128 + lane * 2);
      *op = make_float2(o0, o1);
    }
  }
}

extern "C" void kernel_launch(void* const* d_in, const int* in_sizes, int n_in,
                              void* d_out, int out_size, void* d_ws, size_t ws_size,
                              hipStream_t stream) {
  const float* x = (const float*)d_in[0];
  const float* W = (const float*)d_in[1];
  const float* a = (const float*)d_in[2];
  const int* edge = (const int*)d_in[3];
  const int* src = edge;
  const int* dst = edge + NE;
  float* out = (float*)d_out;

  // workspace layout (~50 MB)
  char* p = (char*)d_ws;
  unsigned short* hb = (unsigned short*)p;  p += (size_t)ROWS * 128 * 2;   // 40.96 MB
  float* g1 = (float*)p;                    p += (size_t)ROWS * 4;
  float* g2 = (float*)p;                    p += (size_t)ROWS * 4;
  int* cursor = (int*)p;                    p += (size_t)NN * 4;
  int* ell = (int*)p;                       p += (size_t)NN * ELLW * 4;   // 7.68 MB
  unsigned short* Wb = (unsigned short*)p;  p += (size_t)FI * FO * 2;
  unsigned int* bar = (unsigned int*)p;     p += 8 * 4;

  init_kernel<<<80, 256, 0, stream>>>(W, Wb, cursor, bar);
  mega_kernel<<<NBLK, NTHR, 0, stream>>>(x, Wb, a, src, dst, hb, g1, g2,
                                         cursor, ell, bar, out);
}

// Round 9
// 255.206 us; speedup vs baseline: 2.0310x; 2.0310x over previous
//
#include <hip/hip_runtime.h>

#define NB 8
#define NN 20000
#define FI 128
#define FO 128
#define NE 320000
#define ROWS (NB * NN)        // 160000 flattened (b,n) rows
#define LRALPHA 0.2f
#define ELLW 96               // max degree slot; Poisson(16) tail ~1e-43

typedef short bf16x8 __attribute__((ext_vector_type(8)));
typedef float f32x4 __attribute__((ext_vector_type(4)));

static __device__ __forceinline__ float b2f(unsigned short u) {
  return __uint_as_float(((unsigned int)u) << 16);
}
static __device__ __forceinline__ unsigned short f2b(float f) {
  unsigned int u = __float_as_uint(f);
  return (unsigned short)((u + 0x7FFFu + ((u >> 16) & 1u)) >> 16);  // RNE
}

// ---- W transpose: W[k][o] fp32 -> Wb[o][k] bf16; also zero ELL cursor -----
__global__ __launch_bounds__(256) void wt_kernel(const float* __restrict__ W,
                                                 unsigned short* __restrict__ Wb,
                                                 int* __restrict__ cursor) {
  int idx = blockIdx.x * 256 + threadIdx.x;  // 80 blocks -> 20480 threads
  if (idx < FI * FO) {
    int k = idx >> 7, o = idx & 127;
    Wb[o * 128 + k] = f2b(W[idx]);
  }
  if (idx < NN) cursor[idx] = 0;
}

// ---- GEMM: W in padded LDS (round-0 verified); hb[b][n][128] bf16 ---------
#define LDW 136  // padded LDS stride: m-stride 272B -> 2-way bank alias (free)

__global__ __launch_bounds__(256) void gemm_kernel(
    const float* __restrict__ x, const unsigned short* __restrict__ Wb,
    const float* __restrict__ a,
    unsigned short* __restrict__ hb,
    float* __restrict__ g1, float* __restrict__ g2) {
  __shared__ __align__(16) unsigned short Ws[128 * LDW];  // 34.8 KB
  const int tid = threadIdx.x;

  // stage Wb (already bf16, [o][k]) into padded LDS: coalesced 16B chunks
  {
    const bf16x8* wsrc = (const bf16x8*)Wb;
#pragma unroll
    for (int it = 0; it < 8; ++it) {
      int c = tid + it * 256;          // 16B chunk id, 0..2047
      int o = c >> 4, seg = c & 15;
      *(bf16x8*)&Ws[o * LDW + seg * 8] = wsrc[c];
    }
  }

  const int wv = tid >> 6;
  const int lane = tid & 63;
  const int m = lane & 15;
  const int quad = lane >> 4;
  const size_t row0 = (size_t)blockIdx.x * 64 + wv * 16;  // wave's first row

  // A-fragments: x[row0+m][k0*32 + quad*8 .. +8] fp32 -> bf16 in-reg
  const float* xr = x + (row0 + m) * 128;
  bf16x8 afr[4];
#pragma unroll
  for (int k0 = 0; k0 < 4; ++k0) {
    const float4* xp = (const float4*)(xr + k0 * 32 + quad * 8);
    float4 v0 = xp[0];
    float4 v1 = xp[1];
    union { bf16x8 v; unsigned short u[8]; } af;
    af.u[0] = f2b(v0.x); af.u[1] = f2b(v0.y);
    af.u[2] = f2b(v0.z); af.u[3] = f2b(v0.w);
    af.u[4] = f2b(v1.x); af.u[5] = f2b(v1.y);
    af.u[6] = f2b(v1.z); af.u[7] = f2b(v1.w);
    afr[k0] = af.v;
  }
  __syncthreads();

  f32x4 acc[8] = {};
#pragma unroll
  for (int k0 = 0; k0 < 4; ++k0) {
#pragma unroll
    for (int c = 0; c < 8; ++c) {
      bf16x8 bf = *(const bf16x8*)&Ws[(c * 16 + m) * LDW + k0 * 32 + quad * 8];
      acc[c] = __builtin_amdgcn_mfma_f32_16x16x32_bf16(afr[k0], bf, acc[c], 0, 0, 0);
    }
  }

  // C/D layout: col = lane&15 (within c-tile), row = quad*4 + r
  unsigned short* hp = hb + row0 * 128;
#pragma unroll
  for (int c = 0; c < 8; ++c)
#pragma unroll
    for (int r = 0; r < 4; ++r)
      hp[(quad * 4 + r) * 128 + c * 16 + m] = f2b(acc[c][r]);

  // fused g1/g2: per-row dot with a1/a2 from fp32 accumulators
  float a1v[8], a2v[8];
#pragma unroll
  for (int c = 0; c < 8; ++c) {
    a1v[c] = a[c * 16 + m];
    a2v[c] = a[128 + c * 16 + m];
  }
  float p1[4] = {}, p2[4] = {};
#pragma unroll
  for (int c = 0; c < 8; ++c)
#pragma unroll
    for (int r = 0; r < 4; ++r) {
      p1[r] = fmaf(acc[c][r], a1v[c], p1[r]);
      p2[r] = fmaf(acc[c][r], a2v[c], p2[r]);
    }
#pragma unroll
  for (int off = 1; off < 16; off <<= 1)
#pragma unroll
    for (int r = 0; r < 4; ++r) {
      p1[r] += __shfl_xor(p1[r], off, 64);
      p2[r] += __shfl_xor(p2[r], off, 64);
    }
  if (m == 0) {
    size_t rbase = row0 + quad * 4;
#pragma unroll
    for (int r = 0; r < 4; ++r) {
      g1[rbase + r] = p1[r];
      g2[rbase + r] = p2[r];
    }
  }
}

// ---- ELL scatter: one pass, replaces hist+scan+scatter --------------------
__global__ __launch_bounds__(256) void ell_scatter_kernel(
    const int* __restrict__ src, const int* __restrict__ dst,
    int* __restrict__ cursor, int* __restrict__ ell) {
  int e = blockIdx.x * 256 + threadIdx.x;
  if (e < NE) {
    int s = src[e];
    int d = dst[e];
    int slot = atomicAdd(&cursor[s], 1);
    if (slot < ELLW) ell[s * ELLW + slot] = d;   // overflow impossible; clamp for safety
  }
}

// ---------------- gather: readlane broadcast, no LDS ops in inner loop ------
// Wave = (node i, batch b), b = bid&7 XCD-affine over batch-major hb.
// Lane l owns cols [2l, 2l+1]. Edge broadcast via v_readlane (VALU->SGPR):
// no ds_bpermute, no lgkm waits; broadcast d folds into the load's scalar
// base. rs accumulated from uniform wj -> identical in all lanes -> NO
// cross-lane reduce at all. Per edge: 7 VALU + 1 VMEM dword (256B/wave).
__global__ __launch_bounds__(256) void gather_kernel(
    const unsigned short* __restrict__ hb, const float* __restrict__ g1,
    const float* __restrict__ g2, const int* __restrict__ degs,
    const int* __restrict__ ell, float* __restrict__ out) {
  const int bid = blockIdx.x;
  const int b = bid & 7;                     // XCD-affine batch
  const int wv = threadIdx.x >> 6;
  const int i = (bid >> 3) * 4 + wv;         // node for this wave
  const int lane = threadIdx.x & 63;
  const int deg = min(degs[i], ELLW);        // >= 1 (src contains arange(N))
  const int base = i * ELLW;
  const float g1i = g1[(size_t)b * NN + i];
  const float* g2b = g2 + (size_t)b * NN;
  // lane's dword (cols 2l, 2l+1) within any h-row of batch b
  const char* hrow = (const char*)(hb + (size_t)b * NN * 128) + lane * 4;

  float accLo = 0.f, accHi = 0.f;
  float rs = 0.f;
  for (int c0 = 0; c0 < deg; c0 += 64) {
    const int cnt = min(64, deg - c0);
    const int li = lane < cnt ? lane : cnt - 1;
    const int dvec = ell[base + c0 + li];    // coalesced chunk of dst indices
    float w = 0.f;
    if (lane < cnt) {
      float sv = g1i + g2b[dvec];            // L2-resident 4B gather
      float sc = fmaxf(sv, LRALPHA * sv);
      w = __expf(-sc);
    }
    const int cr = (cnt + 3) & ~3;           // pad: lanes >= cnt carry w=0
    for (int j = 0; j < cr; j += 4) {
#pragma unroll
      for (int jj = 0; jj < 4; ++jj) {
        const int sel = j + jj;
        float wj = __int_as_float(
            __builtin_amdgcn_readlane(__float_as_int(w), sel));
        int dj = __builtin_amdgcn_readlane(dvec, sel);
        unsigned int u = *(const unsigned int*)(hrow + ((size_t)dj << 8));
        rs += wj;                            // uniform: no reduce needed
        accLo = fmaf(wj, __uint_as_float(u << 16), accLo);
        accHi = fmaf(wj, __uint_as_float(u & 0xFFFF0000u), accHi);
      }
    }
  }

  const float inv = 1.f / rs;
  float v0 = accLo * inv;
  float v1 = accHi * inv;
  float o0 = v0 > 0.f ? v0 : __expf(v0) - 1.f;   // elu (alpha=1)
  float o1 = v1 > 0.f ? v1 : __expf(v1) - 1.f;
  float2* op = (float2*)(out + ((size_t)b * NN + i) * 128 + lane * 2);
  *op = make_float2(o0, o1);
}

extern "C" void kernel_launch(void* const* d_in, const int* in_sizes, int n_in,
                              void* d_out, int out_size, void* d_ws, size_t ws_size,
                              hipStream_t stream) {
  const float* x = (const float*)d_in[0];
  const float* W = (const float*)d_in[1];
  const float* a = (const float*)d_in[2];
  const int* edge = (const int*)d_in[3];
  const int* src = edge;
  const int* dst = edge + NE;
  float* out = (float*)d_out;

  // workspace layout (~50 MB)
  char* p = (char*)d_ws;
  unsigned short* hb = (unsigned short*)p;  p += (size_t)ROWS * 128 * 2;   // 40.96 MB
  float* g1 = (float*)p;                    p += (size_t)ROWS * 4;
  float* g2 = (float*)p;                    p += (size_t)ROWS * 4;
  int* cursor = (int*)p;                    p += (size_t)NN * 4;
  int* ell = (int*)p;                       p += (size_t)NN * ELLW * 4;   // 7.68 MB
  unsigned short* Wb = (unsigned short*)p;  p += (size_t)FI * FO * 2;

  wt_kernel<<<80, 256, 0, stream>>>(W, Wb, cursor);  // also zeroes cursor
  gemm_kernel<<<ROWS / 64, 256, 0, stream>>>(x, Wb, a, hb, g1, g2);
  ell_scatter_kernel<<<(NE + 255) / 256, 256, 0, stream>>>(src, dst, cursor, ell);
  gather_kernel<<<(NN / 4) * NB, 256, 0, stream>>>(hb, g1, g2, cursor, ell, out);
}